// Round 3
// baseline (315.385 us; speedup 1.0000x reference)
//
#include <hip/hip_runtime.h>

#define BB 32
#define HH 512
#define WW 512
#define HW (HH * WW)
#define NPIX (BB * HW)

#define TILE 64
#define MR 80            // m/q source region (halo 8)
#define MQ 20            // float4 quads per m row
#define ER 72            // lm/e region (halo 4)
#define EQ 18            // quads per e row

// ---------------------------------------------------------------------------
// Kernel A (fused): per 64x64 tile
//   phase 1: load x (80x80 region, 3ch) -> m (80x80), q (72x72) in LDS
//   phase 2: blur m -> lm (72x72); write interior lm to global;
//            e = max(q - lm*(2m-lm), 0) in-place over q (zero outside image)
//   phase 3: blur e -> sigma (64x64) -> global; block sigma-sum -> partials
// ---------------------------------------------------------------------------
__global__ __launch_bounds__(256) void k_fused(const float4* __restrict__ x4,
                                               const float* __restrict__ kw,
                                               float* __restrict__ lm_g,
                                               float* __restrict__ sg_g,
                                               float* __restrict__ partials) {
    __shared__ float sm[MR * MR];    // channel-mean, 80x80
    __shared__ float sqe[ER * ER];   // q then e in place, 72x72
    __shared__ float kk[81];
    __shared__ float wsum[4];
    const int tx = threadIdx.x, ty = threadIdx.y;      // 16 x 16
    const int tid = ty * 16 + tx;
    if (tid < 81) kk[tid] = kw[tid];
    const int x0 = blockIdx.x * TILE, y0 = blockIdx.y * TILE;
    const int bz = blockIdx.z;
    const float4* xb = x4 + (size_t)bz * (HW * 3 / 4);

    // ---- phase 1: 1600 groups of 4 pixels (3 float4 loads each) ----
    const float t3 = 1.f / 3.f;
    for (int i = tid; i < MR * MQ; i += 256) {
        int r = i / MQ, g = i - r * MQ;
        int gy = y0 + r - 8, gx = x0 + 4 * g - 8;
        float4 m = make_float4(0.f, 0.f, 0.f, 0.f);
        float4 q = make_float4(0.f, 0.f, 0.f, 0.f);
        if (gy >= 0 && gy < HH && gx >= 0 && gx < WW) {
            int qi = (3 * (gy * WW + gx)) >> 2;
            float4 a = xb[qi], b = xb[qi + 1], c = xb[qi + 2];
            m.x = (a.x + a.y + a.z) * t3;  q.x = (a.x * a.x + a.y * a.y + a.z * a.z) * t3;
            m.y = (a.w + b.x + b.y) * t3;  q.y = (a.w * a.w + b.x * b.x + b.y * b.y) * t3;
            m.z = (b.z + b.w + c.x) * t3;  q.z = (b.z * b.z + b.w * b.w + c.x * c.x) * t3;
            m.w = (c.y + c.z + c.w) * t3;  q.w = (c.y * c.y + c.z * c.z + c.w * c.w) * t3;
        }
        *(float4*)&sm[r * MR + 4 * g] = m;
        if (r >= 4 && r < 76 && g >= 1 && g < 19)
            *(float4*)&sqe[(r - 4) * ER + 4 * g - 4] = q;
    }
    __syncthreads();

    // ---- phase 2: blur m -> lm over 72x72 (18x18 tiles of 4 rows x 1 quad) ----
    const size_t boff = (size_t)bz * HW;
    for (int tI = tid; tI < EQ * EQ; tI += 256) {
        int g2 = tI / EQ, qc = tI - g2 * EQ;
        int rb = 4 * g2;
        float acc[4][4] = {};
        const float4* m4 = (const float4*)sm;
#pragma unroll
        for (int rr = 0; rr < 12; ++rr) {
            int rowq = (rb + rr) * MQ + qc;
            float4 a = m4[rowq], b = m4[rowq + 1], c = m4[rowq + 2];
            float f[12] = {a.x, a.y, a.z, a.w, b.x, b.y, b.z, b.w, c.x, c.y, c.z, c.w};
#pragma unroll
            for (int ky = 0; ky < 9; ++ky) {
                int my = rr - ky;
                if (my < 0 || my > 3) continue;
#pragma unroll
                for (int kx = 0; kx < 9; ++kx) {
                    float w = kk[ky * 9 + kx];
#pragma unroll
                    for (int mx = 0; mx < 4; ++mx)
                        acc[my][mx] = fmaf(w, f[kx + mx], acc[my][mx]);
                }
            }
        }
        int px = x0 + 4 * qc - 4;                    // absolute image x of quad
#pragma unroll
        for (int my = 0; my < 4; ++my) {
            int er = rb + my;                        // e-region row
            int py = y0 + er - 4;                    // absolute image y
            float4 l = make_float4(acc[my][0], acc[my][1], acc[my][2], acc[my][3]);
            // interior lm -> global (tile-relative coords in [0,64))
            if (er >= 4 && er < 68 && qc >= 1 && qc < 17)
                *(float4*)&lm_g[boff + (size_t)py * WW + px] = l;
            // e = max(q - lm*(2m - lm), 0), zero outside image
            float4 e = make_float4(0.f, 0.f, 0.f, 0.f);
            if (py >= 0 && py < HH && px >= 0 && px < WW) {
                float4 q = *(const float4*)&sqe[er * ER + 4 * qc];
                const float4 mm = *(const float4*)&sm[(er + 4) * MR + 4 * qc + 4];
                e.x = fmaxf(q.x - l.x * (2.f * mm.x - l.x), 0.f);
                e.y = fmaxf(q.y - l.y * (2.f * mm.y - l.y), 0.f);
                e.z = fmaxf(q.z - l.z * (2.f * mm.z - l.z), 0.f);
                e.w = fmaxf(q.w - l.w * (2.f * mm.w - l.w), 0.f);
            }
            *(float4*)&sqe[er * ER + 4 * qc] = e;
        }
    }
    __syncthreads();

    // ---- phase 3: blur e -> sigma, 4x4 micro-tile per thread ----
    float acc[4][4] = {};
    const float4* e4 = (const float4*)sqe;
#pragma unroll
    for (int rr = 0; rr < 12; ++rr) {
        int rowq = (4 * ty + rr) * EQ + tx;
        float4 a = e4[rowq], b = e4[rowq + 1], c = e4[rowq + 2];
        float f[12] = {a.x, a.y, a.z, a.w, b.x, b.y, b.z, b.w, c.x, c.y, c.z, c.w};
#pragma unroll
        for (int ky = 0; ky < 9; ++ky) {
            int my = rr - ky;
            if (my < 0 || my > 3) continue;
#pragma unroll
            for (int kx = 0; kx < 9; ++kx) {
                float w = kk[ky * 9 + kx];
#pragma unroll
                for (int mx = 0; mx < 4; ++mx)
                    acc[my][mx] = fmaf(w, f[kx + mx], acc[my][mx]);
            }
        }
    }
    float s = 0.f;
    float* dp = sg_g + boff + (size_t)(y0 + 4 * ty) * WW + x0 + 4 * tx;
#pragma unroll
    for (int my = 0; my < 4; ++my) {
        float4 o;
        o.x = sqrtf(fmaxf(acc[my][0], 0.f));
        o.y = sqrtf(fmaxf(acc[my][1], 0.f));
        o.z = sqrtf(fmaxf(acc[my][2], 0.f));
        o.w = sqrtf(fmaxf(acc[my][3], 0.f));
        *(float4*)(dp + my * WW) = o;
        s += o.x + o.y + o.z + o.w;
    }
#pragma unroll
    for (int off = 32; off > 0; off >>= 1) s += __shfl_down(s, off);
    if ((tid & 63) == 0) wsum[tid >> 6] = s;
    __syncthreads();
    if (tid == 0)
        partials[bz * 64 + blockIdx.y * 8 + blockIdx.x] =
            wsum[0] + wsum[1] + wsum[2] + wsum[3];
}

// ---------------------------------------------------------------------------
// Kernel B: reduce 64 partials -> mean_sigma, then
// out = (x - lm) / max(mean_sigma, sigma). Thread = 4 pixels, float4 IO.
// ---------------------------------------------------------------------------
__global__ __launch_bounds__(256) void k_norm(const float4* __restrict__ x4,
                                              const float4* __restrict__ lm4,
                                              const float4* __restrict__ sg4,
                                              const float* __restrict__ partials,
                                              float4* __restrict__ out4) {
    __shared__ float ms_s;
    const int tid = threadIdx.x;
    const int b = blockIdx.x >> 8;            // 256 blocks per batch image
    if (tid < 64) {
        float p = partials[b * 64 + tid];
#pragma unroll
        for (int off = 32; off > 0; off >>= 1) p += __shfl_down(p, off);
        if (tid == 0) ms_s = p * (1.f / (float)HW);
    }
    __syncthreads();
    float ms = ms_s;
    int g = blockIdx.x * 256 + tid;
    float4 l = lm4[g];
    float4 s = sg4[g];
    float i0 = 1.f / fmaxf(ms, s.x);
    float i1 = 1.f / fmaxf(ms, s.y);
    float i2 = 1.f / fmaxf(ms, s.z);
    float i3 = 1.f / fmaxf(ms, s.w);
    float4 a = x4[3 * g + 0];
    float4 bb = x4[3 * g + 1];
    float4 c = x4[3 * g + 2];
    float4 o0, o1, o2;
    o0.x = (a.x - l.x) * i0;  o0.y = (a.y - l.x) * i0;  o0.z = (a.z - l.x) * i0;
    o0.w = (a.w - l.y) * i1;  o1.x = (bb.x - l.y) * i1; o1.y = (bb.y - l.y) * i1;
    o1.z = (bb.z - l.z) * i2; o1.w = (bb.w - l.z) * i2; o2.x = (c.x - l.z) * i2;
    o2.y = (c.y - l.w) * i3;  o2.z = (c.z - l.w) * i3;  o2.w = (c.w - l.w) * i3;
    out4[3 * g + 0] = o0;
    out4[3 * g + 1] = o1;
    out4[3 * g + 2] = o2;
}

extern "C" void kernel_launch(void* const* d_in, const int* in_sizes, int n_in,
                              void* d_out, int out_size, void* d_ws, size_t ws_size,
                              hipStream_t stream) {
    const float* x = (const float*)d_in[0];
    const float* kw = (const float*)d_in[1];
    float* out = (float*)d_out;
    float* wsp = (float*)d_ws;
    float* lm       = wsp + 0 * (size_t)NPIX;
    float* sg       = wsp + 1 * (size_t)NPIX;
    float* partials = wsp + 2 * (size_t)NPIX;   // 2048 floats

    dim3 blk(16, 16);
    dim3 grd(WW / TILE, HH / TILE, BB);
    k_fused<<<grd, blk, 0, stream>>>((const float4*)x, kw, lm, sg, partials);

    const int ngrp = NPIX / 4;
    k_norm<<<ngrp / 256, 256, 0, stream>>>((const float4*)x, (const float4*)lm,
                                           (const float4*)sg, partials, (float4*)out);
}